// Round 12
// baseline (266.087 us; speedup 1.0000x reference)
//
#include <hip/hip_runtime.h>
#include <hip/hip_bf16.h>

typedef unsigned short u16;
typedef float f32x4 __attribute__((ext_vector_type(4)));
typedef short s16x8 __attribute__((ext_vector_type(8)));

#define NB 4
#define NN 20000
#define NE 320000
#define ROWS (NB*NN)          // 80000
#define GBLK 1250             // gate blocks: 16 nodes x 4 batches each
#define SLOTCAP 64            // max degree capacity (Poisson(16): P(>64) ~ 1e-20)
#define XTBLK 5000            // xt role blocks in setup

__device__ __forceinline__ float b2f(u16 u){
  union{unsigned int i; float f;} v; v.i = ((unsigned int)u)<<16; return v.f;
}
__device__ __forceinline__ u16 f2b(float f){
  __hip_bfloat16 h = __float2bfloat16(f);
  return __builtin_bit_cast(u16, h);
}

// ---------------- K1: setup — xt transpose (blocks 0..4999), prep (5000..5005),
//                   zero deg/cursor (5006..5084) ----------------
__global__ void __launch_bounds__(256) setup_kernel(
    const float* __restrict__ x, ushort4* __restrict__ xt4,
    const float* Wz, const float* bz, const float* Lz, const float* lbz,
    const float* Wr, const float* br, const float* Lr, const float* lbr,
    const float* Wh, const float* bh, const float* Lh, const float* lbh,
    int4* __restrict__ wfrag, float* __restrict__ cvec,
    float* __restrict__ deg, int* __restrict__ cursor){
  int bid = blockIdx.x;
  if(bid < XTBLK){
    int t = bid*256 + threadIdx.x;   // 0 .. NB*NN*16-1 (exactly 1.28M = 5000*256)
    int b = t / (NN*16);
    int rem = t - b*(NN*16);
    int n = rem >> 4;
    int c4 = rem & 15;
    float4 v = reinterpret_cast<const float4*>(x)[t];
    ushort4 o; o.x=f2b(v.x); o.y=f2b(v.y); o.z=f2b(v.z); o.w=f2b(v.w);
    xt4[(size_t)n*64 + b*16 + c4] = o;
  } else if(bid < XTBLK+6){
    int m = bid - XTBLK;       // 0..5
    int g = m >> 1, half = m & 1;
    const float* W  = (g==0)?Wz:(g==1)?Wr:Wh;
    const float* L  = (g==0)?Lz:(g==1)?Lr:Lh;
    const float* bb = (g==0)?bz:(g==1)?br:bh;
    const float* lb = (g==0)?lbz:(g==1)?lbr:lbh;
    __shared__ __align__(16) float Wl[4096];
    __shared__ __align__(16) float Lt[4096];
    __shared__ __align__(16) float Pr[4096];
    int t = threadIdx.x;
    if(half == 0){
      for(int i=t; i<1024; i+=256){
        reinterpret_cast<float4*>(Wl)[i] = reinterpret_cast<const float4*>(W)[i];
        reinterpret_cast<float4*>(Lt)[i] = reinterpret_cast<const float4*>(L)[i];
      }
      __syncthreads();
      for(int q=0; q<16; q++){
        int idx = t + 256*q;
        int i = idx>>6, j = idx&63;
        float acc = 0.f;
        for(int k=0;k<64;k++) acc += Wl[i*64+k] * Lt[k*64+j];
        Pr[idx] = acc;
      }
      if(t < 64){
        float a = lb[t];
        for(int k=0;k<64;k++) a += bb[k]*Lt[k*64+t];
        cvec[g*64 + t] = a;
      }
    } else {
      for(int i=t; i<1024; i+=256)
        reinterpret_cast<float4*>(Pr)[i] = reinterpret_cast<const float4*>(L + 4096)[i];
    }
    __syncthreads();
    for(int it=t; it<512; it+=256){
      int l  = it & 63;
      int rl = it >> 6;          // s*4 + tt
      int s  = rl >> 2, tt = rl & 3;
      int k0 = s*32 + (l>>4)*8;
      int n  = tt*16 + (l&15);
      union { u16 v[8]; int4 q4; } tmp;
      #pragma unroll
      for(int j=0;j<8;j++) tmp.v[j] = f2b(Pr[(k0+j)*64 + n]);
      wfrag[m*512 + it] = tmp.q4;
    }
  } else {
    int i = (bid - (XTBLK+6))*256 + threadIdx.x;
    if(i < NN){ deg[i]=0.f; cursor[i]=0; }
  }
}

// ---------------- K2: slotted edge scatter ----------
__global__ void fillslots_kernel(const int* __restrict__ ei, const float* __restrict__ ew,
                                 float* deg, int* cursor, int2* __restrict__ slots){
  int e = blockIdx.x*blockDim.x + threadIdx.x;
  if(e >= NE) return;
  int s = ei[e], d = ei[NE + e];
  float w = ew[e];
  atomicAdd(&deg[d], w);
  int p = atomicAdd(&cursor[d], 1);
  if(p < SLOTCAP){
    int2 ent; ent.x = s; ent.y = __float_as_int(w);
    slots[d*SLOTCAP + p] = ent;
  }
}

__device__ __forceinline__ float dinvf(float d){
  return (d > 0.f) ? rsqrtf(fmaxf(d, 1e-12f)) : 0.f;
}

// ---------------- K3: fused aggregation + GRU gate + pool partials (MFMA) --------
// Block = nodes [blk*16, blk*16+16) x all 4 batches. Phase 1: 4 waves aggregate
// 4 nodes each from slots into LDS (8 KB). Phase 2: wave w = batch w runs the
// MFMA gate pipeline reading A-fragments from LDS.
#define LDW(m,s,t) __builtin_bit_cast(s16x8, wfrag[((m)*8+(s)*4+(t))*64 + lane])

__global__ void __launch_bounds__(256, 4) gate_kernel(
    const ushort4* __restrict__ xt4, const float* __restrict__ deg,
    const int* __restrict__ cursor, const int2* __restrict__ slots,
    const float* __restrict__ H,
    const int4* __restrict__ wfrag, const float* __restrict__ cvec,
    const float* __restrict__ gate_w, const float* __restrict__ gate_b,
    float* __restrict__ Hnew, float* __restrict__ ypart, float* __restrict__ dpart)
{
  __shared__ ushort4 aglds[16][64];                 // 8 KB aggregated tile (node-local x (b,c4))
  __shared__ __align__(16) u16 rlds[4][1152];       // per-wave R tile, 16 rows x 72 (padded)
  __shared__ float ylds[4][64];                     // per-wave (=per-batch) pool partials
  __shared__ float dlds[4];

  const int warp = threadIdx.x >> 6, lane = threadIdx.x & 63;
  const int mrow = lane & 15, quad = lane >> 4;
  const int blk = blockIdx.x;            // 0..1249
  const int n0 = blk*16;

  // ---- Phase 1: aggregate 4 nodes per wave into LDS ----
  #pragma unroll
  for(int i=0;i<4;i++){
    int nl = warp*4 + i;                 // node-local 0..15
    int node = n0 + nl;
    int cnt = min(cursor[node], SLOTCAP);
    float dn = dinvf(deg[node]);
    const int2* sl = slots + node*SLOTCAP;
    float a0=0.f, a1=0.f, a2=0.f, a3=0.f;
    int j = 0;
    for(; j+3 < cnt; j+=4){
      int2 ea = sl[j],   eb = sl[j+1];
      int2 ec = sl[j+2], ed = sl[j+3];
      ushort4 va = xt4[(size_t)ea.x*64 + lane];
      ushort4 vb = xt4[(size_t)eb.x*64 + lane];
      ushort4 vc = xt4[(size_t)ec.x*64 + lane];
      ushort4 vd = xt4[(size_t)ed.x*64 + lane];
      float wa = dinvf(deg[ea.x]) * __int_as_float(ea.y) * dn;
      float wb = dinvf(deg[eb.x]) * __int_as_float(eb.y) * dn;
      float wc = dinvf(deg[ec.x]) * __int_as_float(ec.y) * dn;
      float wd = dinvf(deg[ed.x]) * __int_as_float(ed.y) * dn;
      a0 += wa*b2f(va.x) + wb*b2f(vb.x) + wc*b2f(vc.x) + wd*b2f(vd.x);
      a1 += wa*b2f(va.y) + wb*b2f(vb.y) + wc*b2f(vc.y) + wd*b2f(vd.y);
      a2 += wa*b2f(va.z) + wb*b2f(vb.z) + wc*b2f(vc.z) + wd*b2f(vd.z);
      a3 += wa*b2f(va.w) + wb*b2f(vb.w) + wc*b2f(vc.w) + wd*b2f(vd.w);
    }
    for(; j < cnt; j++){
      int2 e = sl[j];
      float w = dinvf(deg[e.x]) * __int_as_float(e.y) * dn;
      ushort4 v = xt4[(size_t)e.x*64 + lane];
      a0 += w * b2f(v.x);
      a1 += w * b2f(v.y);
      a2 += w * b2f(v.z);
      a3 += w * b2f(v.w);
    }
    ushort4 o; o.x=f2b(a0); o.y=f2b(a1); o.z=f2b(a2); o.w=f2b(a3);
    aglds[nl][lane] = o;
  }

  float czv[4], crv[4], chv[4], gwv[4];
  #pragma unroll
  for(int t=0;t<4;t++){
    czv[t] = cvec[t*16+mrow];
    crv[t] = cvec[64 + t*16+mrow];
    chv[t] = cvec[128 + t*16+mrow];
    gwv[t] = gate_w[t*16+mrow];
  }
  const float gb = gate_b[0];
  __syncthreads();   // aglds ready

  // ---- Phase 2: wave w = batch w, nodes [n0, n0+16) ----
  const int r0 = warp*NN + n0;

  // A-fragments from LDS: channels quad*8..+7 -> ushort4 cols warp*16 + quad*2 (+1);
  // channels 32+quad*8 -> cols warp*16 + 8 + quad*2 (+1)
  s16x8 a0 = __builtin_bit_cast(s16x8, *reinterpret_cast<const int4*>(&aglds[mrow][warp*16 + quad*2]));
  s16x8 a1 = __builtin_bit_cast(s16x8, *reinterpret_cast<const int4*>(&aglds[mrow][warp*16 + 8 + quad*2]));

  const float* Hrow = H + (size_t)(r0+mrow)*64;
  union { f32x4 v4[2]; float f[8]; } u0, u1;
  u0.v4[0] = *reinterpret_cast<const f32x4*>(Hrow + quad*8);
  u0.v4[1] = *reinterpret_cast<const f32x4*>(Hrow + quad*8 + 4);
  u1.v4[0] = *reinterpret_cast<const f32x4*>(Hrow + 32 + quad*8);
  u1.v4[1] = *reinterpret_cast<const f32x4*>(Hrow + 32 + quad*8 + 4);
  s16x8 h0, h1;
  #pragma unroll
  for(int j=0;j<8;j++){
    h0[j] = (short)f2b(u0.f[j]);
    h1[j] = (short)f2b(u1.f[j]);
  }

  f32x4 Zc[4], Rc[4], Hc[4];
  #pragma unroll
  for(int t=0;t<4;t++){
    f32x4 acc = {0.f,0.f,0.f,0.f};
    acc = __builtin_amdgcn_mfma_f32_16x16x32_bf16(a0, LDW(0,0,t), acc, 0,0,0);
    acc = __builtin_amdgcn_mfma_f32_16x16x32_bf16(a1, LDW(0,1,t), acc, 0,0,0);
    acc = __builtin_amdgcn_mfma_f32_16x16x32_bf16(h0, LDW(1,0,t), acc, 0,0,0);
    acc = __builtin_amdgcn_mfma_f32_16x16x32_bf16(h1, LDW(1,1,t), acc, 0,0,0);
    Zc[t] = acc;
    f32x4 ar = {0.f,0.f,0.f,0.f};
    ar = __builtin_amdgcn_mfma_f32_16x16x32_bf16(a0, LDW(2,0,t), ar, 0,0,0);
    ar = __builtin_amdgcn_mfma_f32_16x16x32_bf16(a1, LDW(2,1,t), ar, 0,0,0);
    ar = __builtin_amdgcn_mfma_f32_16x16x32_bf16(h0, LDW(3,0,t), ar, 0,0,0);
    ar = __builtin_amdgcn_mfma_f32_16x16x32_bf16(h1, LDW(3,1,t), ar, 0,0,0);
    Rc[t] = ar;
    f32x4 ah = {0.f,0.f,0.f,0.f};
    ah = __builtin_amdgcn_mfma_f32_16x16x32_bf16(a0, LDW(4,0,t), ah, 0,0,0);
    ah = __builtin_amdgcn_mfma_f32_16x16x32_bf16(a1, LDW(4,1,t), ah, 0,0,0);
    Hc[t] = ah;
  }

  // sigmoid(R) -> LDS (C-layout write); per-warp buffer, in-wave ordering.
  #pragma unroll
  for(int t=0;t<4;t++){
    #pragma unroll
    for(int i=0;i<4;i++){
      float r = 1.f/(1.f + __expf(-(Rc[t][i] + crv[t])));
      rlds[warp][(quad*4+i)*72 + t*16 + mrow] = f2b(r);
    }
  }
  const u16* rp = &rlds[warp][mrow*72 + quad*8];
  int4 rv0 = *reinterpret_cast<const int4*>(rp);
  int4 rv1 = *reinterpret_cast<const int4*>(rp + 32);
  const u16* rv0p = reinterpret_cast<const u16*>(&rv0);
  const u16* rv1p = reinterpret_cast<const u16*>(&rv1);
  s16x8 hr0, hr1;
  #pragma unroll
  for(int j=0;j<8;j++){
    hr0[j] = (short)f2b(u0.f[j] * b2f(rv0p[j]));
    hr1[j] = (short)f2b(u1.f[j] * b2f(rv1p[j]));
  }
  #pragma unroll
  for(int t=0;t<4;t++){
    Hc[t] = __builtin_amdgcn_mfma_f32_16x16x32_bf16(hr0, LDW(5,0,t), Hc[t], 0,0,0);
    Hc[t] = __builtin_amdgcn_mfma_f32_16x16x32_bf16(hr1, LDW(5,1,t), Hc[t], 0,0,0);
  }

  // epilogue: Z, Ht, H_new, gate logits, pool partials
  float hnv[4][4];
  float ga[4] = {0.f,0.f,0.f,0.f};
  #pragma unroll
  for(int t=0;t<4;t++){
    #pragma unroll
    for(int i=0;i<4;i++){
      int row = r0 + quad*4 + i, col = t*16 + mrow;
      float z  = 1.f/(1.f + __expf(-(Zc[t][i] + czv[t])));
      float ht = tanhf(Hc[t][i] + chv[t]);
      float hv = H[(size_t)row*64 + col];
      float hn = z*hv + (1.f - z)*ht;
      Hnew[(size_t)row*64 + col] = hn;
      hnv[t][i] = hn;
      ga[i] += hn * gwv[t];
    }
  }
  #pragma unroll
  for(int i=0;i<4;i++){
    float v = ga[i];
    v += __shfl_xor(v, 1, 64);
    v += __shfl_xor(v, 2, 64);
    v += __shfl_xor(v, 4, 64);
    v += __shfl_xor(v, 8, 64);
    ga[i] = v;
  }
  float e_[4]; float dsum = 0.f;
  #pragma unroll
  for(int i=0;i<4;i++){ e_[i] = __expf(ga[i] + gb); dsum += e_[i]; }
  #pragma unroll
  for(int t=0;t<4;t++){
    float s = 0.f;
    #pragma unroll
    for(int i=0;i<4;i++) s += e_[i]*hnv[t][i];
    s += __shfl_xor(s, 16, 64);
    s += __shfl_xor(s, 32, 64);
    if(lane < 16) ylds[warp][t*16 + mrow] = s;
  }
  dsum += __shfl_xor(dsum, 16, 64);
  dsum += __shfl_xor(dsum, 32, 64);
  if(lane == 0) dlds[warp] = dsum;
  __syncthreads();
  int t = threadIdx.x;
  {
    int wb = t >> 6, col = t & 63;      // 4 batch partials, coalesced
    ypart[((size_t)wb*GBLK + blk)*64 + col] = ylds[wb][col];
  }
  if(t < 4) dpart[t*GBLK + blk] = dlds[t];
}

// ---------------- K4: head — 4 blocks, parallel partial reduce + MLP ----------
__global__ void __launch_bounds__(256) head_kernel(
    const float* __restrict__ ypart, const float* __restrict__ dpart,
    const float* W1, const float* b1,
    const float* W2, const float* b2, float* out){
  __shared__ float red[4][64];
  __shared__ float yv[64];
  __shared__ float hid[64];
  __shared__ float dshared;
  int b = blockIdx.x, t = threadIdx.x;
  int d = t & 63, q = t >> 6;
  const float* yp = ypart + (size_t)b*GBLK*64;
  float s = 0.f;
  #pragma unroll 4
  for(int k=q; k<GBLK; k+=4) s += yp[k*64 + d];
  red[q][d] = s;
  if(t < 64){
    const float* dp = dpart + b*GBLK;
    float ds = 0.f;
    for(int k=t; k<GBLK; k+=64) ds += dp[k];
    ds += __shfl_xor(ds, 1, 64);
    ds += __shfl_xor(ds, 2, 64);
    ds += __shfl_xor(ds, 4, 64);
    ds += __shfl_xor(ds, 8, 64);
    ds += __shfl_xor(ds, 16, 64);
    ds += __shfl_xor(ds, 32, 64);
    if(t == 0) dshared = ds;
  }
  __syncthreads();
  if(t < 64) yv[t] = red[0][t] + red[1][t] + red[2][t] + red[3][t];
  __syncthreads();
  if(t < 64){
    float inv = 1.f / dshared;
    float acc = b1[t];
    #pragma unroll 4
    for(int k=0;k<64;k++) acc += (yv[k]*inv) * W1[k*64+t];
    hid[t] = fmaxf(acc, 0.f);
  }
  __syncthreads();
  if(t < 32){
    float a2 = b2[t];
    #pragma unroll 4
    for(int d2=0; d2<64; d2++) a2 += hid[d2] * W2[d2*32+t];
    out[b*32+t] = a2;
  }
}

// ---------------- launch ----------------
extern "C" void kernel_launch(void* const* d_in, const int* in_sizes, int n_in,
                              void* d_out, int out_size, void* d_ws, size_t ws_size,
                              hipStream_t stream) {
  const float* x   = (const float*)d_in[0];
  const int*   ei  = (const int*)d_in[1];
  const float* ew  = (const float*)d_in[2];
  const float* H   = (const float*)d_in[3];
  const float* Wz = (const float*)d_in[4],  *bz = (const float*)d_in[5];
  const float* Wr = (const float*)d_in[6],  *br = (const float*)d_in[7];
  const float* Wh = (const float*)d_in[8],  *bh = (const float*)d_in[9];
  const float* Lz = (const float*)d_in[10], *lbz = (const float*)d_in[11];
  const float* Lr = (const float*)d_in[12], *lbr = (const float*)d_in[13];
  const float* Lh = (const float*)d_in[14], *lbh = (const float*)d_in[15];
  const float* gw = (const float*)d_in[16], *gbp = (const float*)d_in[17];
  const float* W1 = (const float*)d_in[18], *b1 = (const float*)d_in[19];
  const float* W2 = (const float*)d_in[20], *b2 = (const float*)d_in[21];

  float* y_out    = (float*)d_out;
  float* Hnew_out = (float*)d_out + 128;

  char* ws = (char*)d_ws;
  size_t off = 0;
  auto alloc = [&](size_t bytes)->char*{
    off = (off + 255) & ~(size_t)255;
    char* p = ws + off; off += bytes; return p;
  };
  float*   deg      = (float*)alloc(NN*4);
  int*     cursor   = (int*)  alloc(NN*4);
  int2*    slots    = (int2*) alloc((size_t)NN*SLOTCAP*8);
  ushort4* xt4      = (ushort4*)alloc((size_t)NN*256*2);
  int4*    wfrag    = (int4*) alloc(3072*16);
  float*   cvec     = (float*)alloc(192*4);
  float*   ypart    = (float*)alloc((size_t)NB*GBLK*64*4);
  float*   dpart    = (float*)alloc((size_t)NB*GBLK*4);
  (void)ws_size; (void)n_in; (void)in_sizes; (void)out_size;

  const int zeroblk = (NN + 255)/256;   // 79
  setup_kernel<<<XTBLK + 6 + zeroblk, 256, 0, stream>>>(
      x, xt4, Wz,bz,Lz,lbz, Wr,br,Lr,lbr, Wh,bh,Lh,lbh, wfrag, cvec, deg, cursor);
  fillslots_kernel<<<(NE+255)/256, 256, 0, stream>>>(ei, ew, deg, cursor, slots);
  gate_kernel<<<GBLK, 256, 0, stream>>>(xt4, deg, cursor, slots, H, wfrag, cvec,
                                        gw, gbp, Hnew_out, ypart, dpart);
  head_kernel<<<4, 256, 0, stream>>>(ypart, dpart, W1, b1, W2, b2, y_out);
}

// Round 13
// 240.663 us; speedup vs baseline: 1.1056x; 1.1056x over previous
//
#include <hip/hip_runtime.h>
#include <hip/hip_bf16.h>

typedef unsigned short u16;
typedef float f32x4 __attribute__((ext_vector_type(4)));
typedef short s16x8 __attribute__((ext_vector_type(8)));

#define NB 4
#define NN 20000
#define NE 320000
#define ROWS (NB*NN)          // 80000
#define NBLK 313              // gate blocks per batch (313*4 waves >= 1250 tiles)
#define SLOTCAP 64            // max degree capacity (Poisson(16): P(>64) ~ 1e-20)
#define XTBLK 5000            // xt role blocks in setup

__device__ __forceinline__ float b2f(u16 u){
  union{unsigned int i; float f;} v; v.i = ((unsigned int)u)<<16; return v.f;
}
__device__ __forceinline__ u16 f2b(float f){
  __hip_bfloat16 h = __float2bfloat16(f);
  return __builtin_bit_cast(u16, h);
}

// ---------------- K1: setup — xt transpose (blocks 0..4999), prep (5000..5005),
//                   zero deg/cursor (5006..5084) ----------------
__global__ void __launch_bounds__(256) setup_kernel(
    const float* __restrict__ x, ushort4* __restrict__ xt4,
    const float* Wz, const float* bz, const float* Lz, const float* lbz,
    const float* Wr, const float* br, const float* Lr, const float* lbr,
    const float* Wh, const float* bh, const float* Lh, const float* lbh,
    int4* __restrict__ wfrag, float* __restrict__ cvec,
    float* __restrict__ deg, int* __restrict__ cursor){
  int bid = blockIdx.x;
  if(bid < XTBLK){
    int t = bid*256 + threadIdx.x;   // 0 .. NB*NN*16-1 (exactly 1.28M = 5000*256)
    int b = t / (NN*16);
    int rem = t - b*(NN*16);
    int n = rem >> 4;
    int c4 = rem & 15;
    float4 v = reinterpret_cast<const float4*>(x)[t];
    ushort4 o; o.x=f2b(v.x); o.y=f2b(v.y); o.z=f2b(v.z); o.w=f2b(v.w);
    xt4[(size_t)n*64 + b*16 + c4] = o;
  } else if(bid < XTBLK+6){
    int m = bid - XTBLK;       // 0..5
    int g = m >> 1, half = m & 1;
    const float* W  = (g==0)?Wz:(g==1)?Wr:Wh;
    const float* L  = (g==0)?Lz:(g==1)?Lr:Lh;
    const float* bb = (g==0)?bz:(g==1)?br:bh;
    const float* lb = (g==0)?lbz:(g==1)?lbr:lbh;
    __shared__ __align__(16) float Wl[4096];
    __shared__ __align__(16) float Lt[4096];
    __shared__ __align__(16) float Pr[4096];
    int t = threadIdx.x;
    if(half == 0){
      for(int i=t; i<1024; i+=256){
        reinterpret_cast<float4*>(Wl)[i] = reinterpret_cast<const float4*>(W)[i];
        reinterpret_cast<float4*>(Lt)[i] = reinterpret_cast<const float4*>(L)[i];
      }
      __syncthreads();
      for(int q=0; q<16; q++){
        int idx = t + 256*q;
        int i = idx>>6, j = idx&63;
        float acc = 0.f;
        for(int k=0;k<64;k++) acc += Wl[i*64+k] * Lt[k*64+j];
        Pr[idx] = acc;
      }
      if(t < 64){
        float a = lb[t];
        for(int k=0;k<64;k++) a += bb[k]*Lt[k*64+t];
        cvec[g*64 + t] = a;
      }
    } else {
      for(int i=t; i<1024; i+=256)
        reinterpret_cast<float4*>(Pr)[i] = reinterpret_cast<const float4*>(L + 4096)[i];
    }
    __syncthreads();
    for(int it=t; it<512; it+=256){
      int l  = it & 63;
      int rl = it >> 6;          // s*4 + tt
      int s  = rl >> 2, tt = rl & 3;
      int k0 = s*32 + (l>>4)*8;
      int n  = tt*16 + (l&15);
      union { u16 v[8]; int4 q4; } tmp;
      #pragma unroll
      for(int j=0;j<8;j++) tmp.v[j] = f2b(Pr[(k0+j)*64 + n]);
      wfrag[m*512 + it] = tmp.q4;
    }
  } else {
    int i = (bid - (XTBLK+6))*256 + threadIdx.x;
    if(i < NN){ deg[i]=0.f; cursor[i]=0; }
  }
}

// ---------------- K2: slotted edge scatter ----------
__global__ void fillslots_kernel(const int* __restrict__ ei, const float* __restrict__ ew,
                                 float* deg, int* cursor, int2* __restrict__ slots){
  int e = blockIdx.x*blockDim.x + threadIdx.x;
  if(e >= NE) return;
  int s = ei[e], d = ei[NE + e];
  float w = ew[e];
  atomicAdd(&deg[d], w);
  int p = atomicAdd(&cursor[d], 1);
  if(p < SLOTCAP){
    int2 ent; ent.x = s; ent.y = __float_as_int(w);
    slots[d*SLOTCAP + p] = ent;
  }
}

__device__ __forceinline__ float dinvf(float d){
  return (d > 0.f) ? rsqrtf(fmaxf(d, 1e-12f)) : 0.f;
}

// ---------------- K3: per-node aggregation, 2 waves per node ----------
// 10000 blocks x 4 waves: waves (2k,2k+1) split node k's slots by parity,
// combine via LDS. Doubles gather TLP vs wave-per-node (lesson from R12:
// latency-bound gather wants more independent waves).
__global__ void agg_kernel(const ushort4* __restrict__ xt4, const float* __restrict__ deg,
                           const int* __restrict__ cursor, const int2* __restrict__ slots,
                           u16* __restrict__ agg){
  __shared__ float comb[4][4][64];
  int warp = threadIdx.x >> 6, lane = threadIdx.x & 63;
  int node = blockIdx.x*2 + (warp >> 1);      // 0..19999
  int half = warp & 1;
  int cnt = min(cursor[node], SLOTCAP);
  float dn = dinvf(deg[node]);
  const int2* sl = slots + node*SLOTCAP;
  float a0=0.f, a1=0.f, a2=0.f, a3=0.f;
  int j = half;
  for(; j+6 < cnt; j+=8){
    int2 ea = sl[j],   eb = sl[j+2];
    int2 ec = sl[j+4], ed = sl[j+6];
    ushort4 va = xt4[(size_t)ea.x*64 + lane];
    ushort4 vb = xt4[(size_t)eb.x*64 + lane];
    ushort4 vc = xt4[(size_t)ec.x*64 + lane];
    ushort4 vd = xt4[(size_t)ed.x*64 + lane];
    float wa = dinvf(deg[ea.x]) * __int_as_float(ea.y) * dn;
    float wb = dinvf(deg[eb.x]) * __int_as_float(eb.y) * dn;
    float wc = dinvf(deg[ec.x]) * __int_as_float(ec.y) * dn;
    float wd = dinvf(deg[ed.x]) * __int_as_float(ed.y) * dn;
    a0 += wa*b2f(va.x) + wb*b2f(vb.x) + wc*b2f(vc.x) + wd*b2f(vd.x);
    a1 += wa*b2f(va.y) + wb*b2f(vb.y) + wc*b2f(vc.y) + wd*b2f(vd.y);
    a2 += wa*b2f(va.z) + wb*b2f(vb.z) + wc*b2f(vc.z) + wd*b2f(vd.z);
    a3 += wa*b2f(va.w) + wb*b2f(vb.w) + wc*b2f(vc.w) + wd*b2f(vd.w);
  }
  for(; j < cnt; j+=2){
    int2 e = sl[j];
    float w = dinvf(deg[e.x]) * __int_as_float(e.y) * dn;
    ushort4 v = xt4[(size_t)e.x*64 + lane];
    a0 += w * b2f(v.x);
    a1 += w * b2f(v.y);
    a2 += w * b2f(v.z);
    a3 += w * b2f(v.w);
  }
  comb[warp][0][lane]=a0; comb[warp][1][lane]=a1;
  comb[warp][2][lane]=a2; comb[warp][3][lane]=a3;
  __syncthreads();
  if(half == 0){
    a0 += comb[warp+1][0][lane];
    a1 += comb[warp+1][1][lane];
    a2 += comb[warp+1][2][lane];
    a3 += comb[warp+1][3][lane];
    int b = lane >> 4, c4 = lane & 15;
    ushort4 o; o.x=f2b(a0); o.y=f2b(a1); o.z=f2b(a2); o.w=f2b(a3);
    reinterpret_cast<ushort4*>(agg)[((size_t)b*NN + node)*16 + c4] = o;
  }
}

// ---------------- K4: fused GRU gate + pool partials (MFMA) ----------------
#define LDW(m,s,t) __builtin_bit_cast(s16x8, wfrag[((m)*8+(s)*4+(t))*64 + lane])

__global__ void __launch_bounds__(256, 4) gate_kernel(
    const u16* __restrict__ agg, const float* __restrict__ H,
    const int4* __restrict__ wfrag, const float* __restrict__ cvec,
    const float* __restrict__ gate_w, const float* __restrict__ gate_b,
    float* __restrict__ Hnew, float* __restrict__ ypart, float* __restrict__ dpart)
{
  __shared__ __align__(16) u16 rlds[4][1152];       // per-wave R tile, 16 rows x 72 (padded)
  __shared__ float ylds[4][64];                     // per-wave pool partials
  __shared__ float dlds[4];

  const int warp = threadIdx.x >> 6, lane = threadIdx.x & 63;
  const int mrow = lane & 15, quad = lane >> 4;
  const int bat = blockIdx.x / NBLK;
  const int blk = blockIdx.x % NBLK;
  const int tin = blk*4 + warp;           // tile within batch, 0..1251
  const bool valid = (tin < 1250);
  const int r0 = bat*NN + tin*16;         // global row (guarded by valid)

  float czv[4], crv[4], chv[4], gwv[4];
  #pragma unroll
  for(int t=0;t<4;t++){
    czv[t] = cvec[t*16+mrow];
    crv[t] = cvec[64 + t*16+mrow];
    chv[t] = cvec[128 + t*16+mrow];
    gwv[t] = gate_w[t*16+mrow];
  }
  const float gb = gate_b[0];

  f32x4 Zc[4], Rc[4], Hc[4];
  union { f32x4 v4[2]; float f[8]; } u0, u1;
  if(valid){
    const int4* ap = reinterpret_cast<const int4*>(agg + (size_t)(r0+mrow)*64);
    s16x8 a0 = __builtin_bit_cast(s16x8, ap[quad]);
    s16x8 a1 = __builtin_bit_cast(s16x8, ap[4+quad]);

    const float* Hrow = H + (size_t)(r0+mrow)*64;
    u0.v4[0] = *reinterpret_cast<const f32x4*>(Hrow + quad*8);
    u0.v4[1] = *reinterpret_cast<const f32x4*>(Hrow + quad*8 + 4);
    u1.v4[0] = *reinterpret_cast<const f32x4*>(Hrow + 32 + quad*8);
    u1.v4[1] = *reinterpret_cast<const f32x4*>(Hrow + 32 + quad*8 + 4);
    s16x8 h0, h1;
    #pragma unroll
    for(int j=0;j<8;j++){
      h0[j] = (short)f2b(u0.f[j]);
      h1[j] = (short)f2b(u1.f[j]);
    }

    #pragma unroll
    for(int t=0;t<4;t++){
      f32x4 acc = {0.f,0.f,0.f,0.f};
      acc = __builtin_amdgcn_mfma_f32_16x16x32_bf16(a0, LDW(0,0,t), acc, 0,0,0);
      acc = __builtin_amdgcn_mfma_f32_16x16x32_bf16(a1, LDW(0,1,t), acc, 0,0,0);
      acc = __builtin_amdgcn_mfma_f32_16x16x32_bf16(h0, LDW(1,0,t), acc, 0,0,0);
      acc = __builtin_amdgcn_mfma_f32_16x16x32_bf16(h1, LDW(1,1,t), acc, 0,0,0);
      Zc[t] = acc;
      f32x4 ar = {0.f,0.f,0.f,0.f};
      ar = __builtin_amdgcn_mfma_f32_16x16x32_bf16(a0, LDW(2,0,t), ar, 0,0,0);
      ar = __builtin_amdgcn_mfma_f32_16x16x32_bf16(a1, LDW(2,1,t), ar, 0,0,0);
      ar = __builtin_amdgcn_mfma_f32_16x16x32_bf16(h0, LDW(3,0,t), ar, 0,0,0);
      ar = __builtin_amdgcn_mfma_f32_16x16x32_bf16(h1, LDW(3,1,t), ar, 0,0,0);
      Rc[t] = ar;
      f32x4 ah = {0.f,0.f,0.f,0.f};
      ah = __builtin_amdgcn_mfma_f32_16x16x32_bf16(a0, LDW(4,0,t), ah, 0,0,0);
      ah = __builtin_amdgcn_mfma_f32_16x16x32_bf16(a1, LDW(4,1,t), ah, 0,0,0);
      Hc[t] = ah;
    }

    // sigmoid(R) -> LDS (C-layout write); per-warp buffer, in-wave ordering.
    #pragma unroll
    for(int t=0;t<4;t++){
      #pragma unroll
      for(int i=0;i<4;i++){
        float r = 1.f/(1.f + __expf(-(Rc[t][i] + crv[t])));
        rlds[warp][(quad*4+i)*72 + t*16 + mrow] = f2b(r);
      }
    }
    const u16* rp = &rlds[warp][mrow*72 + quad*8];
    int4 rv0 = *reinterpret_cast<const int4*>(rp);
    int4 rv1 = *reinterpret_cast<const int4*>(rp + 32);
    const u16* rv0p = reinterpret_cast<const u16*>(&rv0);
    const u16* rv1p = reinterpret_cast<const u16*>(&rv1);
    s16x8 hr0, hr1;
    #pragma unroll
    for(int j=0;j<8;j++){
      hr0[j] = (short)f2b(u0.f[j] * b2f(rv0p[j]));
      hr1[j] = (short)f2b(u1.f[j] * b2f(rv1p[j]));
    }
    #pragma unroll
    for(int t=0;t<4;t++){
      Hc[t] = __builtin_amdgcn_mfma_f32_16x16x32_bf16(hr0, LDW(5,0,t), Hc[t], 0,0,0);
      Hc[t] = __builtin_amdgcn_mfma_f32_16x16x32_bf16(hr1, LDW(5,1,t), Hc[t], 0,0,0);
    }

    // epilogue: Z, Ht, H_new, gate logits, pool partials
    float hnv[4][4];
    float ga[4] = {0.f,0.f,0.f,0.f};
    #pragma unroll
    for(int t=0;t<4;t++){
      #pragma unroll
      for(int i=0;i<4;i++){
        int row = r0 + quad*4 + i, col = t*16 + mrow;
        float z  = 1.f/(1.f + __expf(-(Zc[t][i] + czv[t])));
        float ht = tanhf(Hc[t][i] + chv[t]);
        float hv = H[(size_t)row*64 + col];
        float hn = z*hv + (1.f - z)*ht;
        Hnew[(size_t)row*64 + col] = hn;
        hnv[t][i] = hn;
        ga[i] += hn * gwv[t];
      }
    }
    #pragma unroll
    for(int i=0;i<4;i++){
      float v = ga[i];
      v += __shfl_xor(v, 1, 64);
      v += __shfl_xor(v, 2, 64);
      v += __shfl_xor(v, 4, 64);
      v += __shfl_xor(v, 8, 64);
      ga[i] = v;
    }
    float e_[4]; float dsum = 0.f;
    #pragma unroll
    for(int i=0;i<4;i++){ e_[i] = __expf(ga[i] + gb); dsum += e_[i]; }
    #pragma unroll
    for(int t=0;t<4;t++){
      float s = 0.f;
      #pragma unroll
      for(int i=0;i<4;i++) s += e_[i]*hnv[t][i];
      s += __shfl_xor(s, 16, 64);
      s += __shfl_xor(s, 32, 64);
      if(lane < 16) ylds[warp][t*16 + mrow] = s;
    }
    dsum += __shfl_xor(dsum, 16, 64);
    dsum += __shfl_xor(dsum, 32, 64);
    if(lane == 0) dlds[warp] = dsum;
  } else {
    if(lane < 16){
      #pragma unroll
      for(int t=0;t<4;t++) ylds[warp][t*16 + mrow] = 0.f;
    }
    if(lane == 0) dlds[warp] = 0.f;
  }
  __syncthreads();
  int t = threadIdx.x;
  if(t < 64){
    float s = ylds[0][t] + ylds[1][t] + ylds[2][t] + ylds[3][t];
    ypart[(size_t)blockIdx.x*64 + t] = s;
  }
  if(t == 64) dpart[blockIdx.x] = dlds[0] + dlds[1] + dlds[2] + dlds[3];
}

// ---------------- K5: head — 4 blocks, parallel partial reduce + MLP ----------
__global__ void __launch_bounds__(256) head_kernel(
    const float* __restrict__ ypart, const float* __restrict__ dpart,
    const float* W1, const float* b1,
    const float* W2, const float* b2, float* out){
  __shared__ float red[4][64];
  __shared__ float yv[64];
  __shared__ float hid[64];
  __shared__ float dshared;
  int b = blockIdx.x, t = threadIdx.x;
  int d = t & 63, q = t >> 6;
  const float* yp = ypart + (size_t)b*NBLK*64;
  float s = 0.f;
  #pragma unroll 4
  for(int k=q; k<NBLK; k+=4) s += yp[k*64 + d];
  red[q][d] = s;
  if(t < 64){
    const float* dp = dpart + b*NBLK;
    float ds = 0.f;
    for(int k=t; k<NBLK; k+=64) ds += dp[k];
    ds += __shfl_xor(ds, 1, 64);
    ds += __shfl_xor(ds, 2, 64);
    ds += __shfl_xor(ds, 4, 64);
    ds += __shfl_xor(ds, 8, 64);
    ds += __shfl_xor(ds, 16, 64);
    ds += __shfl_xor(ds, 32, 64);
    if(t == 0) dshared = ds;
  }
  __syncthreads();
  if(t < 64) yv[t] = red[0][t] + red[1][t] + red[2][t] + red[3][t];
  __syncthreads();
  if(t < 64){
    float inv = 1.f / dshared;
    float acc = b1[t];
    #pragma unroll 4
    for(int k=0;k<64;k++) acc += (yv[k]*inv) * W1[k*64+t];
    hid[t] = fmaxf(acc, 0.f);
  }
  __syncthreads();
  if(t < 32){
    float a2 = b2[t];
    #pragma unroll 4
    for(int d2=0; d2<64; d2++) a2 += hid[d2] * W2[d2*32+t];
    out[b*32+t] = a2;
  }
}

// ---------------- launch ----------------
extern "C" void kernel_launch(void* const* d_in, const int* in_sizes, int n_in,
                              void* d_out, int out_size, void* d_ws, size_t ws_size,
                              hipStream_t stream) {
  const float* x   = (const float*)d_in[0];
  const int*   ei  = (const int*)d_in[1];
  const float* ew  = (const float*)d_in[2];
  const float* H   = (const float*)d_in[3];
  const float* Wz = (const float*)d_in[4],  *bz = (const float*)d_in[5];
  const float* Wr = (const float*)d_in[6],  *br = (const float*)d_in[7];
  const float* Wh = (const float*)d_in[8],  *bh = (const float*)d_in[9];
  const float* Lz = (const float*)d_in[10], *lbz = (const float*)d_in[11];
  const float* Lr = (const float*)d_in[12], *lbr = (const float*)d_in[13];
  const float* Lh = (const float*)d_in[14], *lbh = (const float*)d_in[15];
  const float* gw = (const float*)d_in[16], *gbp = (const float*)d_in[17];
  const float* W1 = (const float*)d_in[18], *b1 = (const float*)d_in[19];
  const float* W2 = (const float*)d_in[20], *b2 = (const float*)d_in[21];

  float* y_out    = (float*)d_out;
  float* Hnew_out = (float*)d_out + 128;

  char* ws = (char*)d_ws;
  size_t off = 0;
  auto alloc = [&](size_t bytes)->char*{
    off = (off + 255) & ~(size_t)255;
    char* p = ws + off; off += bytes; return p;
  };
  float*   deg      = (float*)alloc(NN*4);
  int*     cursor   = (int*)  alloc(NN*4);
  int2*    slots    = (int2*) alloc((size_t)NN*SLOTCAP*8);
  ushort4* xt4      = (ushort4*)alloc((size_t)NN*256*2);
  u16*     agg      = (u16*)  alloc((size_t)ROWS*64*2);
  int4*    wfrag    = (int4*) alloc(3072*16);
  float*   cvec     = (float*)alloc(192*4);
  float*   ypart    = (float*)alloc((size_t)NB*NBLK*64*4);
  float*   dpart    = (float*)alloc((size_t)NB*NBLK*4);
  (void)ws_size; (void)n_in; (void)in_sizes; (void)out_size;

  const int zeroblk = (NN + 255)/256;   // 79
  setup_kernel<<<XTBLK + 6 + zeroblk, 256, 0, stream>>>(
      x, xt4, Wz,bz,Lz,lbz, Wr,br,Lr,lbr, Wh,bh,Lh,lbh, wfrag, cvec, deg, cursor);
  fillslots_kernel<<<(NE+255)/256, 256, 0, stream>>>(ei, ew, deg, cursor, slots);
  agg_kernel<<<NN/2, 256, 0, stream>>>(xt4, deg, cursor, slots, agg);
  gate_kernel<<<NB*NBLK, 256, 0, stream>>>(agg, H, wfrag, cvec, gw, gbp, Hnew_out, ypart, dpart);
  head_kernel<<<4, 256, 0, stream>>>(ypart, dpart, W1, b1, W2, b2, y_out);
}

// Round 14
// 224.974 us; speedup vs baseline: 1.1827x; 1.0697x over previous
//
#include <hip/hip_runtime.h>
#include <hip/hip_bf16.h>

typedef unsigned short u16;
typedef float f32x4 __attribute__((ext_vector_type(4)));
typedef short s16x8 __attribute__((ext_vector_type(8)));

#define NB 4
#define NN 20000
#define NE 320000
#define ROWS (NB*NN)          // 80000
#define NBLK 313              // gate blocks per batch (313*4 waves >= 1250 tiles)
#define SLOTCAP 64            // max degree capacity (Poisson(16): P(>64) ~ 1e-20)
#define XTBLK 5000            // xt role blocks in setup
#define FSBLK 1250            // fillslots role blocks (NE/256)

__device__ __forceinline__ float b2f(u16 u){
  union{unsigned int i; float f;} v; v.i = ((unsigned int)u)<<16; return v.f;
}
__device__ __forceinline__ u16 f2b(float f){
  __hip_bfloat16 h = __float2bfloat16(f);
  return __builtin_bit_cast(u16, h);
}

// ---------------- K1: setup — xt transpose (blocks 0..4999), prep (5000..5005),
//                   slotted edge scatter (5006..6255; deg/cursor pre-zeroed by memset) ----
__global__ void __launch_bounds__(256) setup_kernel(
    const float* __restrict__ x, ushort4* __restrict__ xt4,
    const float* Wz, const float* bz, const float* Lz, const float* lbz,
    const float* Wr, const float* br, const float* Lr, const float* lbr,
    const float* Wh, const float* bh, const float* Lh, const float* lbh,
    int4* __restrict__ wfrag, float* __restrict__ cvec,
    const int* __restrict__ ei, const float* __restrict__ ew,
    float* __restrict__ deg, int* __restrict__ cursor, int2* __restrict__ slots){
  int bid = blockIdx.x;
  if(bid < XTBLK){
    int t = bid*256 + threadIdx.x;   // 0 .. NB*NN*16-1 (exactly 1.28M = 5000*256)
    int b = t / (NN*16);
    int rem = t - b*(NN*16);
    int n = rem >> 4;
    int c4 = rem & 15;
    float4 v = reinterpret_cast<const float4*>(x)[t];
    ushort4 o; o.x=f2b(v.x); o.y=f2b(v.y); o.z=f2b(v.z); o.w=f2b(v.w);
    xt4[(size_t)n*64 + b*16 + c4] = o;
  } else if(bid < XTBLK+6){
    int m = bid - XTBLK;       // 0..5
    int g = m >> 1, half = m & 1;
    const float* W  = (g==0)?Wz:(g==1)?Wr:Wh;
    const float* L  = (g==0)?Lz:(g==1)?Lr:Lh;
    const float* bb = (g==0)?bz:(g==1)?br:bh;
    const float* lb = (g==0)?lbz:(g==1)?lbr:lbh;
    __shared__ __align__(16) float Wl[4096];
    __shared__ __align__(16) float Lt[4096];
    __shared__ __align__(16) float Pr[4096];
    int t = threadIdx.x;
    if(half == 0){
      for(int i=t; i<1024; i+=256){
        reinterpret_cast<float4*>(Wl)[i] = reinterpret_cast<const float4*>(W)[i];
        reinterpret_cast<float4*>(Lt)[i] = reinterpret_cast<const float4*>(L)[i];
      }
      __syncthreads();
      for(int q=0; q<16; q++){
        int idx = t + 256*q;
        int i = idx>>6, j = idx&63;
        float acc = 0.f;
        for(int k=0;k<64;k++) acc += Wl[i*64+k] * Lt[k*64+j];
        Pr[idx] = acc;
      }
      if(t < 64){
        float a = lb[t];
        for(int k=0;k<64;k++) a += bb[k]*Lt[k*64+t];
        cvec[g*64 + t] = a;
      }
    } else {
      for(int i=t; i<1024; i+=256)
        reinterpret_cast<float4*>(Pr)[i] = reinterpret_cast<const float4*>(L + 4096)[i];
    }
    __syncthreads();
    for(int it=t; it<512; it+=256){
      int l  = it & 63;
      int rl = it >> 6;          // s*4 + tt
      int s  = rl >> 2, tt = rl & 3;
      int k0 = s*32 + (l>>4)*8;
      int n  = tt*16 + (l&15);
      union { u16 v[8]; int4 q4; } tmp;
      #pragma unroll
      for(int j=0;j<8;j++) tmp.v[j] = f2b(Pr[(k0+j)*64 + n]);
      wfrag[m*512 + it] = tmp.q4;
    }
  } else {
    int e = (bid - (XTBLK+6))*256 + threadIdx.x;
    if(e < NE){
      int s = ei[e], d = ei[NE + e];
      float w = ew[e];
      atomicAdd(&deg[d], w);
      int p = atomicAdd(&cursor[d], 1);
      if(p < SLOTCAP){
        int2 ent; ent.x = s; ent.y = __float_as_int(w);
        slots[d*SLOTCAP + p] = ent;
      }
    }
  }
}

__device__ __forceinline__ float dinvf(float d){
  return (d > 0.f) ? rsqrtf(fmaxf(d, 1e-12f)) : 0.f;
}

// ---------------- K2: per-node aggregation (wave per node, 4x unrolled) ----------
__global__ void agg_kernel(const ushort4* __restrict__ xt4, const float* __restrict__ deg,
                           const int* __restrict__ cursor, const int2* __restrict__ slots,
                           u16* __restrict__ agg){
  int wave = (blockIdx.x*blockDim.x + threadIdx.x) >> 6;
  int lane = threadIdx.x & 63;
  if(wave >= NN) return;
  int cnt = min(cursor[wave], SLOTCAP);
  float dn = dinvf(deg[wave]);
  const int2* sl = slots + wave*SLOTCAP;
  float a0=0.f, a1=0.f, a2=0.f, a3=0.f;
  int j = 0;
  for(; j+3 < cnt; j+=4){
    int2 ea = sl[j],   eb = sl[j+1];
    int2 ec = sl[j+2], ed = sl[j+3];
    ushort4 va = xt4[(size_t)ea.x*64 + lane];
    ushort4 vb = xt4[(size_t)eb.x*64 + lane];
    ushort4 vc = xt4[(size_t)ec.x*64 + lane];
    ushort4 vd = xt4[(size_t)ed.x*64 + lane];
    float wa = dinvf(deg[ea.x]) * __int_as_float(ea.y) * dn;
    float wb = dinvf(deg[eb.x]) * __int_as_float(eb.y) * dn;
    float wc = dinvf(deg[ec.x]) * __int_as_float(ec.y) * dn;
    float wd = dinvf(deg[ed.x]) * __int_as_float(ed.y) * dn;
    a0 += wa*b2f(va.x) + wb*b2f(vb.x) + wc*b2f(vc.x) + wd*b2f(vd.x);
    a1 += wa*b2f(va.y) + wb*b2f(vb.y) + wc*b2f(vc.y) + wd*b2f(vd.y);
    a2 += wa*b2f(va.z) + wb*b2f(vb.z) + wc*b2f(vc.z) + wd*b2f(vd.z);
    a3 += wa*b2f(va.w) + wb*b2f(vb.w) + wc*b2f(vc.w) + wd*b2f(vd.w);
  }
  for(; j < cnt; j++){
    int2 e = sl[j];
    float w = dinvf(deg[e.x]) * __int_as_float(e.y) * dn;
    ushort4 v = xt4[(size_t)e.x*64 + lane];
    a0 += w * b2f(v.x);
    a1 += w * b2f(v.y);
    a2 += w * b2f(v.z);
    a3 += w * b2f(v.w);
  }
  int b = lane >> 4, c4 = lane & 15;
  ushort4 o; o.x=f2b(a0); o.y=f2b(a1); o.z=f2b(a2); o.w=f2b(a3);
  reinterpret_cast<ushort4*>(agg)[((size_t)b*NN + wave)*16 + c4] = o;
}

// ---------------- K3: fused GRU gate + pool partials (MFMA) ----------------
#define LDW(m,s,t) __builtin_bit_cast(s16x8, wfrag[((m)*8+(s)*4+(t))*64 + lane])

__global__ void __launch_bounds__(256, 4) gate_kernel(
    const u16* __restrict__ agg, const float* __restrict__ H,
    const int4* __restrict__ wfrag, const float* __restrict__ cvec,
    const float* __restrict__ gate_w, const float* __restrict__ gate_b,
    float* __restrict__ Hnew, float* __restrict__ ypart, float* __restrict__ dpart)
{
  __shared__ __align__(16) u16 rlds[4][1152];       // per-wave R tile, 16 rows x 72 (padded)
  __shared__ float ylds[4][64];                     // per-wave pool partials
  __shared__ float dlds[4];

  const int warp = threadIdx.x >> 6, lane = threadIdx.x & 63;
  const int mrow = lane & 15, quad = lane >> 4;
  const int bat = blockIdx.x / NBLK;
  const int blk = blockIdx.x % NBLK;
  const int tin = blk*4 + warp;           // tile within batch, 0..1251
  const bool valid = (tin < 1250);
  const int r0 = bat*NN + tin*16;         // global row (guarded by valid)

  float czv[4], crv[4], chv[4], gwv[4];
  #pragma unroll
  for(int t=0;t<4;t++){
    czv[t] = cvec[t*16+mrow];
    crv[t] = cvec[64 + t*16+mrow];
    chv[t] = cvec[128 + t*16+mrow];
    gwv[t] = gate_w[t*16+mrow];
  }
  const float gb = gate_b[0];

  f32x4 Zc[4], Rc[4], Hc[4];
  union { f32x4 v4[2]; float f[8]; } u0, u1;
  if(valid){
    const int4* ap = reinterpret_cast<const int4*>(agg + (size_t)(r0+mrow)*64);
    s16x8 a0 = __builtin_bit_cast(s16x8, ap[quad]);
    s16x8 a1 = __builtin_bit_cast(s16x8, ap[4+quad]);

    const float* Hrow = H + (size_t)(r0+mrow)*64;
    u0.v4[0] = *reinterpret_cast<const f32x4*>(Hrow + quad*8);
    u0.v4[1] = *reinterpret_cast<const f32x4*>(Hrow + quad*8 + 4);
    u1.v4[0] = *reinterpret_cast<const f32x4*>(Hrow + 32 + quad*8);
    u1.v4[1] = *reinterpret_cast<const f32x4*>(Hrow + 32 + quad*8 + 4);
    s16x8 h0, h1;
    #pragma unroll
    for(int j=0;j<8;j++){
      h0[j] = (short)f2b(u0.f[j]);
      h1[j] = (short)f2b(u1.f[j]);
    }

    #pragma unroll
    for(int t=0;t<4;t++){
      f32x4 acc = {0.f,0.f,0.f,0.f};
      acc = __builtin_amdgcn_mfma_f32_16x16x32_bf16(a0, LDW(0,0,t), acc, 0,0,0);
      acc = __builtin_amdgcn_mfma_f32_16x16x32_bf16(a1, LDW(0,1,t), acc, 0,0,0);
      acc = __builtin_amdgcn_mfma_f32_16x16x32_bf16(h0, LDW(1,0,t), acc, 0,0,0);
      acc = __builtin_amdgcn_mfma_f32_16x16x32_bf16(h1, LDW(1,1,t), acc, 0,0,0);
      Zc[t] = acc;
      f32x4 ar = {0.f,0.f,0.f,0.f};
      ar = __builtin_amdgcn_mfma_f32_16x16x32_bf16(a0, LDW(2,0,t), ar, 0,0,0);
      ar = __builtin_amdgcn_mfma_f32_16x16x32_bf16(a1, LDW(2,1,t), ar, 0,0,0);
      ar = __builtin_amdgcn_mfma_f32_16x16x32_bf16(h0, LDW(3,0,t), ar, 0,0,0);
      ar = __builtin_amdgcn_mfma_f32_16x16x32_bf16(h1, LDW(3,1,t), ar, 0,0,0);
      Rc[t] = ar;
      f32x4 ah = {0.f,0.f,0.f,0.f};
      ah = __builtin_amdgcn_mfma_f32_16x16x32_bf16(a0, LDW(4,0,t), ah, 0,0,0);
      ah = __builtin_amdgcn_mfma_f32_16x16x32_bf16(a1, LDW(4,1,t), ah, 0,0,0);
      Hc[t] = ah;
    }

    // sigmoid(R) -> LDS (C-layout write); per-warp buffer, in-wave ordering.
    #pragma unroll
    for(int t=0;t<4;t++){
      #pragma unroll
      for(int i=0;i<4;i++){
        float r = 1.f/(1.f + __expf(-(Rc[t][i] + crv[t])));
        rlds[warp][(quad*4+i)*72 + t*16 + mrow] = f2b(r);
      }
    }
    const u16* rp = &rlds[warp][mrow*72 + quad*8];
    int4 rv0 = *reinterpret_cast<const int4*>(rp);
    int4 rv1 = *reinterpret_cast<const int4*>(rp + 32);
    const u16* rv0p = reinterpret_cast<const u16*>(&rv0);
    const u16* rv1p = reinterpret_cast<const u16*>(&rv1);
    s16x8 hr0, hr1;
    #pragma unroll
    for(int j=0;j<8;j++){
      hr0[j] = (short)f2b(u0.f[j] * b2f(rv0p[j]));
      hr1[j] = (short)f2b(u1.f[j] * b2f(rv1p[j]));
    }
    #pragma unroll
    for(int t=0;t<4;t++){
      Hc[t] = __builtin_amdgcn_mfma_f32_16x16x32_bf16(hr0, LDW(5,0,t), Hc[t], 0,0,0);
      Hc[t] = __builtin_amdgcn_mfma_f32_16x16x32_bf16(hr1, LDW(5,1,t), Hc[t], 0,0,0);
    }

    // epilogue: Z, Ht, H_new, gate logits, pool partials
    float hnv[4][4];
    float ga[4] = {0.f,0.f,0.f,0.f};
    #pragma unroll
    for(int t=0;t<4;t++){
      #pragma unroll
      for(int i=0;i<4;i++){
        int row = r0 + quad*4 + i, col = t*16 + mrow;
        float z  = 1.f/(1.f + __expf(-(Zc[t][i] + czv[t])));
        float ht = tanhf(Hc[t][i] + chv[t]);
        float hv = H[(size_t)row*64 + col];
        float hn = z*hv + (1.f - z)*ht;
        Hnew[(size_t)row*64 + col] = hn;
        hnv[t][i] = hn;
        ga[i] += hn * gwv[t];
      }
    }
    #pragma unroll
    for(int i=0;i<4;i++){
      float v = ga[i];
      v += __shfl_xor(v, 1, 64);
      v += __shfl_xor(v, 2, 64);
      v += __shfl_xor(v, 4, 64);
      v += __shfl_xor(v, 8, 64);
      ga[i] = v;
    }
    float e_[4]; float dsum = 0.f;
    #pragma unroll
    for(int i=0;i<4;i++){ e_[i] = __expf(ga[i] + gb); dsum += e_[i]; }
    #pragma unroll
    for(int t=0;t<4;t++){
      float s = 0.f;
      #pragma unroll
      for(int i=0;i<4;i++) s += e_[i]*hnv[t][i];
      s += __shfl_xor(s, 16, 64);
      s += __shfl_xor(s, 32, 64);
      if(lane < 16) ylds[warp][t*16 + mrow] = s;
    }
    dsum += __shfl_xor(dsum, 16, 64);
    dsum += __shfl_xor(dsum, 32, 64);
    if(lane == 0) dlds[warp] = dsum;
  } else {
    if(lane < 16){
      #pragma unroll
      for(int t=0;t<4;t++) ylds[warp][t*16 + mrow] = 0.f;
    }
    if(lane == 0) dlds[warp] = 0.f;
  }
  __syncthreads();
  int t = threadIdx.x;
  if(t < 64){
    float s = ylds[0][t] + ylds[1][t] + ylds[2][t] + ylds[3][t];
    ypart[(size_t)blockIdx.x*64 + t] = s;
  }
  if(t == 64) dpart[blockIdx.x] = dlds[0] + dlds[1] + dlds[2] + dlds[3];
}

// ---------------- K4: head — 4 blocks, parallel partial reduce + MLP ----------
__global__ void __launch_bounds__(256) head_kernel(
    const float* __restrict__ ypart, const float* __restrict__ dpart,
    const float* W1, const float* b1,
    const float* W2, const float* b2, float* out){
  __shared__ float red[4][64];
  __shared__ float yv[64];
  __shared__ float hid[64];
  __shared__ float dshared;
  int b = blockIdx.x, t = threadIdx.x;
  int d = t & 63, q = t >> 6;
  const float* yp = ypart + (size_t)b*NBLK*64;
  float s = 0.f;
  #pragma unroll 4
  for(int k=q; k<NBLK; k+=4) s += yp[k*64 + d];
  red[q][d] = s;
  if(t < 64){
    const float* dp = dpart + b*NBLK;
    float ds = 0.f;
    for(int k=t; k<NBLK; k+=64) ds += dp[k];
    ds += __shfl_xor(ds, 1, 64);
    ds += __shfl_xor(ds, 2, 64);
    ds += __shfl_xor(ds, 4, 64);
    ds += __shfl_xor(ds, 8, 64);
    ds += __shfl_xor(ds, 16, 64);
    ds += __shfl_xor(ds, 32, 64);
    if(t == 0) dshared = ds;
  }
  __syncthreads();
  if(t < 64) yv[t] = red[0][t] + red[1][t] + red[2][t] + red[3][t];
  __syncthreads();
  if(t < 64){
    float inv = 1.f / dshared;
    float acc = b1[t];
    #pragma unroll 4
    for(int k=0;k<64;k++) acc += (yv[k]*inv) * W1[k*64+t];
    hid[t] = fmaxf(acc, 0.f);
  }
  __syncthreads();
  if(t < 32){
    float a2 = b2[t];
    #pragma unroll 4
    for(int d2=0; d2<64; d2++) a2 += hid[d2] * W2[d2*32+t];
    out[b*32+t] = a2;
  }
}

// ---------------- launch ----------------
extern "C" void kernel_launch(void* const* d_in, const int* in_sizes, int n_in,
                              void* d_out, int out_size, void* d_ws, size_t ws_size,
                              hipStream_t stream) {
  const float* x   = (const float*)d_in[0];
  const int*   ei  = (const int*)d_in[1];
  const float* ew  = (const float*)d_in[2];
  const float* H   = (const float*)d_in[3];
  const float* Wz = (const float*)d_in[4],  *bz = (const float*)d_in[5];
  const float* Wr = (const float*)d_in[6],  *br = (const float*)d_in[7];
  const float* Wh = (const float*)d_in[8],  *bh = (const float*)d_in[9];
  const float* Lz = (const float*)d_in[10], *lbz = (const float*)d_in[11];
  const float* Lr = (const float*)d_in[12], *lbr = (const float*)d_in[13];
  const float* Lh = (const float*)d_in[14], *lbh = (const float*)d_in[15];
  const float* gw = (const float*)d_in[16], *gbp = (const float*)d_in[17];
  const float* W1 = (const float*)d_in[18], *b1 = (const float*)d_in[19];
  const float* W2 = (const float*)d_in[20], *b2 = (const float*)d_in[21];

  float* y_out    = (float*)d_out;
  float* Hnew_out = (float*)d_out + 128;

  char* ws = (char*)d_ws;
  size_t off = 0;
  auto alloc = [&](size_t bytes)->char*{
    off = (off + 255) & ~(size_t)255;
    char* p = ws + off; off += bytes; return p;
  };
  float*   deg      = (float*)alloc(NN*4);
  int*     cursor   = (int*)  alloc(NN*4);
  int2*    slots    = (int2*) alloc((size_t)NN*SLOTCAP*8);
  ushort4* xt4      = (ushort4*)alloc((size_t)NN*256*2);
  u16*     agg      = (u16*)  alloc((size_t)ROWS*64*2);
  int4*    wfrag    = (int4*) alloc(3072*16);
  float*   cvec     = (float*)alloc(192*4);
  float*   ypart    = (float*)alloc((size_t)NB*NBLK*64*4);
  float*   dpart    = (float*)alloc((size_t)NB*NBLK*4);
  (void)ws_size; (void)n_in; (void)in_sizes; (void)out_size;

  // pre-zero deg/cursor (graph-capturable async memset; 0x0 == 0.0f == 0)
  hipMemsetAsync(deg, 0, NN*4, stream);
  hipMemsetAsync(cursor, 0, NN*4, stream);

  setup_kernel<<<XTBLK + 6 + FSBLK, 256, 0, stream>>>(
      x, xt4, Wz,bz,Lz,lbz, Wr,br,Lr,lbr, Wh,bh,Lh,lbh, wfrag, cvec,
      ei, ew, deg, cursor, slots);
  agg_kernel<<<(NN+3)/4, 256, 0, stream>>>(xt4, deg, cursor, slots, agg);
  gate_kernel<<<NB*NBLK, 256, 0, stream>>>(agg, H, wfrag, cvec, gw, gbp, Hnew_out, ypart, dpart);
  head_kernel<<<4, 256, 0, stream>>>(ypart, dpart, W1, b1, W2, b2, y_out);
}